// Round 1
// baseline (198.348 us; speedup 1.0000x reference)
//
#include <hip/hip_runtime.h>

typedef short bf16x8 __attribute__((ext_vector_type(8)));
typedef float f32x4  __attribute__((ext_vector_type(4)));
typedef short sh4    __attribute__((ext_vector_type(4)));
typedef float fl4    __attribute__((ext_vector_type(4)));

#define B_N  4
#define C_N  256
#define NH_N 8
#define DK_N 32
#define N_N  1024
#define KN_N 3072

__device__ __forceinline__ short f2bf(float f) {
    union { float f; unsigned u; } v; v.f = f;
    unsigned r = v.u + 0x7fffu + ((v.u >> 16) & 1u);  // RNE
    return (short)(r >> 16);
}

// ---------------- kernel 1: weights fp32 -> bf16 (Wq,Wk,Wv,Wo concat) -------
__global__ __launch_bounds__(256) void wcvt_kernel(
    const float* __restrict__ Wq, const float* __restrict__ Wk,
    const float* __restrict__ Wv, const float* __restrict__ Wo,
    short* __restrict__ dst) {
    int t = blockIdx.x * 256 + threadIdx.x;   // 65536 threads, 4 elems each
    int e = t * 4;
    int m = e >> 16;
    int off = e & 65535;
    const float* src = (m == 0) ? Wq : (m == 1) ? Wk : (m == 2) ? Wv : Wo;
    fl4 v = *reinterpret_cast<const fl4*>(src + off);
    sh4 o;
    o.x = f2bf(v.x); o.y = f2bf(v.y); o.z = f2bf(v.z); o.w = f2bf(v.w);
    *reinterpret_cast<sh4*>(dst + m * 65536 + off) = o;
}

// ------------- kernel 2: Xt[b*3+s][n][c] = bf16(gamma_s * x_s[b][c][n]) -----
__global__ __launch_bounds__(256) void prep_kernel(
    const float* __restrict__ x0, const float* __restrict__ x1,
    const float* __restrict__ x2, const float* __restrict__ g0,
    const float* __restrict__ g1, const float* __restrict__ g2,
    short* __restrict__ Xt) {
    __shared__ float tile[64][65];
    int bs = blockIdx.z; int b = bs / 3; int s = bs - b * 3;
    int c0 = blockIdx.y * 64, n0 = blockIdx.x * 64;
    const float* xs = (s == 0) ? x0 : (s == 1) ? x1 : x2;
    float g = (s == 0) ? g0[0] : (s == 1) ? g1[0] : g2[0];
    int tx = threadIdx.x & 63, ty = threadIdx.x >> 6;
    const float* src = xs + (b * C_N + c0) * N_N + n0;
#pragma unroll
    for (int r = 0; r < 16; ++r) {
        int cl = ty * 16 + r;
        tile[cl][tx] = src[cl * N_N + tx] * g;
    }
    __syncthreads();
    short* dst = Xt + ((size_t)bs * N_N + n0) * C_N + c0;
#pragma unroll
    for (int r = 0; r < 16; ++r) {
        int nl = ty * 16 + r;
        dst[nl * C_N + tx] = f2bf(tile[tx][nl]);
    }
}

// ---------------- kernel 3: QKV GEMM  grid(112 ct, 4 mt, 4 b) ---------------
// ct 0-15: Q (stream 0); 16-63: K (s=(ct-16)/16); 64-111: V
__global__ __launch_bounds__(256) void qkv_kernel(
    const short* __restrict__ Wbf, const float* __restrict__ bq,
    const float* __restrict__ bk, const float* __restrict__ bv,
    const short* __restrict__ Xt, short* __restrict__ Qs,
    short* __restrict__ Ks, short* __restrict__ Vt) {
    int b = blockIdx.z, mt = blockIdx.y, ct = blockIdx.x;
    int lane = threadIdx.x & 63, w = threadIdx.x >> 6;
    int l16 = lane & 15, quad = lane >> 4;

    int type, s, n0;
    if (ct < 16)      { type = 0; s = 0;                 n0 = ct * 64; }
    else if (ct < 64) { type = 1; int c2 = ct - 16; s = c2 >> 4; n0 = (c2 & 15) * 64; }
    else              { type = 2; int c2 = ct - 64; s = c2 >> 4; n0 = (c2 & 15) * 64; }

    const short* A    = Wbf + type * 65536;
    const float* bias = (type == 0) ? bq : (type == 1) ? bk : bv;
    const short* Bsrc = Xt + ((size_t)(b * 3 + s) * N_N + n0) * C_N;

    int m0 = mt * 64;
    int arow = m0 + w * 16 + l16;

    f32x4 acc[4];
#pragma unroll
    for (int i = 0; i < 4; ++i) acc[i] = f32x4{0.f, 0.f, 0.f, 0.f};

#pragma unroll
    for (int kc = 0; kc < 256; kc += 32) {
        bf16x8 a = *reinterpret_cast<const bf16x8*>(A + arow * C_N + kc + quad * 8);
#pragma unroll
        for (int nt = 0; nt < 4; ++nt) {
            bf16x8 bb = *reinterpret_cast<const bf16x8*>(Bsrc + (nt * 16 + l16) * C_N + kc + quad * 8);
            acc[nt] = __builtin_amdgcn_mfma_f32_16x16x32_bf16(a, bb, acc[nt], 0, 0, 0);
        }
    }

    // fold softmax scale AND exp->exp2 conversion into Q
    const float QSCALE = 0.17677669529663687f * 1.4426950408889634f;
#pragma unroll
    for (int r = 0; r < 4; ++r) {
        int row = m0 + w * 16 + quad * 4 + r;
        float bv_ = bias[row];
        int h = row >> 5, d = row & 31;
#pragma unroll
        for (int nt = 0; nt < 4; ++nt) {
            int col = n0 + nt * 16 + l16;
            float v = acc[nt][r] + bv_;
            if (type == 0) {
                v *= QSCALE;
                Qs[((size_t)(b * NH_N + h) * N_N + col) * DK_N + d] = f2bf(v);
            } else if (type == 1) {
                Ks[((size_t)(b * NH_N + h) * KN_N + s * N_N + col) * DK_N + d] = f2bf(v);
            } else {
                Vt[((size_t)(b * NH_N + h) * DK_N + d) * KN_N + s * N_N + col] = f2bf(v);
            }
        }
    }
}

// ---------------- kernel 4: fused attention  grid(32 bh, 16 qt) -------------
__global__ __launch_bounds__(256) void attn_kernel(
    const short* __restrict__ Qs, const short* __restrict__ Ks,
    const short* __restrict__ Vt, short* __restrict__ Ot) {
    __shared__ short K_lds[64][40];       // 80B rows, 16B-aligned
    __shared__ short V_lds[32][72];       // 144B rows, 16B-aligned
    __shared__ short P_lds[4][16][72];    // per-wave private

    int bh = blockIdx.x;
    int b = bh >> 3, h = bh & 7;
    int q0 = blockIdx.y * 64;
    int t = threadIdx.x;
    int lane = t & 63, w = t >> 6;
    int l16 = lane & 15, quad = lane >> 4;

    const short* Qbase = Qs + ((size_t)(b * NH_N + h) * N_N + q0 + w * 16) * DK_N;
    const short* Kbase = Ks + (size_t)(b * NH_N + h) * KN_N * DK_N;
    const short* Vbase = Vt + (size_t)(b * NH_N + h) * DK_N * KN_N;

    // Q fragment lives in registers all kernel (dk=32 = one MFMA K-step)
    bf16x8 a_q = *reinterpret_cast<const bf16x8*>(Qbase + l16 * DK_N + quad * 8);

    f32x4 o_acc[2];
    o_acc[0] = f32x4{0.f, 0.f, 0.f, 0.f};
    o_acc[1] = f32x4{0.f, 0.f, 0.f, 0.f};
    float l_part[4] = {0.f, 0.f, 0.f, 0.f};
    const f32x4 zero = {0.f, 0.f, 0.f, 0.f};

    int krow = t >> 2, kseg = t & 3;   // K tile: 64 rows x 4x16B
    int vrow = t >> 3, vseg = t & 7;   // V tile: 32 rows x 8x16B

    for (int kt = 0; kt < 48; ++kt) {
        int k0 = kt * 64;
        __syncthreads();
        {
            bf16x8 kv = *reinterpret_cast<const bf16x8*>(Kbase + (size_t)(k0 + krow) * DK_N + kseg * 8);
            *reinterpret_cast<bf16x8*>(&K_lds[krow][kseg * 8]) = kv;
            bf16x8 vv = *reinterpret_cast<const bf16x8*>(Vbase + (size_t)vrow * KN_N + k0 + vseg * 8);
            *reinterpret_cast<bf16x8*>(&V_lds[vrow][vseg * 8]) = vv;
        }
        __syncthreads();

        // S = Q K^T  (Q pre-scaled: exp2(S) == exp(score/sqrt(dk)))
        f32x4 sacc[4];
#pragma unroll
        for (int st = 0; st < 4; ++st) {
            bf16x8 bk_ = *reinterpret_cast<const bf16x8*>(&K_lds[st * 16 + l16][quad * 8]);
            sacc[st] = __builtin_amdgcn_mfma_f32_16x16x32_bf16(a_q, bk_, zero, 0, 0, 0);
        }
        // no-max softmax numerator; C-layout -> A-layout via per-wave LDS
#pragma unroll
        for (int st = 0; st < 4; ++st) {
#pragma unroll
            for (int r = 0; r < 4; ++r) {
                float p = __builtin_amdgcn_exp2f(sacc[st][r]);
                l_part[r] += p;
                P_lds[w][quad * 4 + r][st * 16 + l16] = f2bf(p);
            }
        }
        // O += P V
#pragma unroll
        for (int ks = 0; ks < 2; ++ks) {
            bf16x8 a_p = *reinterpret_cast<const bf16x8*>(&P_lds[w][l16][ks * 32 + quad * 8]);
#pragma unroll
            for (int dt = 0; dt < 2; ++dt) {
                bf16x8 b_v = *reinterpret_cast<const bf16x8*>(&V_lds[dt * 16 + l16][ks * 32 + quad * 8]);
                o_acc[dt] = __builtin_amdgcn_mfma_f32_16x16x32_bf16(a_p, b_v, o_acc[dt], 0, 0, 0);
            }
        }
    }

    // rowsum across the 16 lanes of each quad
#pragma unroll
    for (int r = 0; r < 4; ++r) {
        float v = l_part[r];
        v += __shfl_xor(v, 1);
        v += __shfl_xor(v, 2);
        v += __shfl_xor(v, 4);
        v += __shfl_xor(v, 8);
        l_part[r] = 1.0f / v;
    }
#pragma unroll
    for (int dt = 0; dt < 2; ++dt) {
#pragma unroll
        for (int r = 0; r < 4; ++r) {
            int q = q0 + w * 16 + quad * 4 + r;
            int c2 = h * DK_N + dt * 16 + l16;
            Ot[((size_t)b * N_N + q) * C_N + c2] = f2bf(o_acc[dt][r] * l_part[r]);
        }
    }
}

// ---------------- kernel 5: output projection  grid(16 ct, 4 mt, 4 b) -------
__global__ __launch_bounds__(256) void oproj_kernel(
    const short* __restrict__ Wo_bf, const float* __restrict__ bo,
    const short* __restrict__ Ot, float* __restrict__ out) {
    int b = blockIdx.z, mt = blockIdx.y, ct = blockIdx.x;
    int lane = threadIdx.x & 63, w = threadIdx.x >> 6;
    int l16 = lane & 15, quad = lane >> 4;
    int m0 = mt * 64, n0 = ct * 64;
    const short* Bsrc = Ot + ((size_t)b * N_N + n0) * C_N;
    int arow = m0 + w * 16 + l16;

    f32x4 acc[4];
#pragma unroll
    for (int i = 0; i < 4; ++i) acc[i] = f32x4{0.f, 0.f, 0.f, 0.f};

#pragma unroll
    for (int kc = 0; kc < 256; kc += 32) {
        bf16x8 a = *reinterpret_cast<const bf16x8*>(Wo_bf + arow * C_N + kc + quad * 8);
#pragma unroll
        for (int nt = 0; nt < 4; ++nt) {
            bf16x8 bb = *reinterpret_cast<const bf16x8*>(Bsrc + (nt * 16 + l16) * C_N + kc + quad * 8);
            acc[nt] = __builtin_amdgcn_mfma_f32_16x16x32_bf16(a, bb, acc[nt], 0, 0, 0);
        }
    }

#pragma unroll
    for (int r = 0; r < 4; ++r) {
        int row = m0 + w * 16 + quad * 4 + r;
        float bias = bo[row];
#pragma unroll
        for (int nt = 0; nt < 4; ++nt) {
            out[((size_t)b * C_N + row) * N_N + n0 + nt * 16 + l16] = acc[nt][r] + bias;
        }
    }
}

// ---------------------------------------------------------------------------
extern "C" void kernel_launch(void* const* d_in, const int* in_sizes, int n_in,
                              void* d_out, int out_size, void* d_ws, size_t ws_size,
                              hipStream_t stream) {
    const float* x0 = (const float*)d_in[0];
    const float* x1 = (const float*)d_in[1];
    const float* x2 = (const float*)d_in[2];
    const float* g0 = (const float*)d_in[3];
    const float* g1 = (const float*)d_in[4];
    const float* g2 = (const float*)d_in[5];
    const float* Wq = (const float*)d_in[6];
    const float* bq = (const float*)d_in[7];
    const float* Wk = (const float*)d_in[8];
    const float* bk = (const float*)d_in[9];
    const float* Wv = (const float*)d_in[10];
    const float* bv = (const float*)d_in[11];
    const float* Wo = (const float*)d_in[12];
    const float* bo = (const float*)d_in[13];
    float* out = (float*)d_out;

    char* wsb = (char*)d_ws;
    // ws layout (bytes):
    short* Wbf = (short*)(wsb + 0);            //  512 KB: Wq,Wk,Wv,Wo bf16
    short* Xt  = (short*)(wsb + 524288);       // 6 MB: [12][1024][256]
    short* Qs  = (short*)(wsb + 6815744);      // 2 MB: [4][8][1024][32]
    short* Ks  = (short*)(wsb + 8912896);      // 6 MB: [4][8][3072][32]
    short* Vt  = (short*)(wsb + 15204352);     // 6 MB: [4][8][32][3072]
    short* Ot  = (short*)(wsb + 21495808);     // 2 MB: [4][1024][256]

    wcvt_kernel<<<256, 256, 0, stream>>>(Wq, Wk, Wv, Wo, Wbf);
    prep_kernel<<<dim3(16, 4, 12), 256, 0, stream>>>(x0, x1, x2, g0, g1, g2, Xt);
    qkv_kernel<<<dim3(112, 4, 4), 256, 0, stream>>>(Wbf, bq, bk, bv, Xt, Qs, Ks, Vt);
    attn_kernel<<<dim3(32, 16), 256, 0, stream>>>(Qs, Ks, Vt, Ot);
    oproj_kernel<<<dim3(16, 4, 4), 256, 0, stream>>>(Qs ? Wbf + 3 * 65536 : Wbf, bo, Ot, out);
}